// Round 23
// baseline (899.504 us; speedup 1.0000x reference)
//
#include <hip/hip_runtime.h>
#include <math.h>

typedef __bf16 bf16x8 __attribute__((ext_vector_type(8)));
typedef float f32x4 __attribute__((ext_vector_type(4)));
typedef short s16x4 __attribute__((ext_vector_type(4)));
typedef short s16x8 __attribute__((ext_vector_type(8)));

static __device__ __forceinline__ short f2bs(float f) {
  return __builtin_bit_cast(short, (__bf16)f);
}
static __device__ __forceinline__ float bs2f(short s) {
  return __builtin_bit_cast(float, ((unsigned int)(unsigned short)s) << 16);
}

#define GLL16(gp, lp) __builtin_amdgcn_global_load_lds( \
    (const __attribute__((address_space(1))) void*)(gp), \
    (__attribute__((address_space(3))) void*)(lp), 16, 0, 0)

// ---------------------------------------------------------------- conversions
// 4 weight tensors f32->bf16 in ONE launch; blockIdx.y selects segment.
// 8 elements/thread: 2x float4 loads (32B/lane) + 1x s16x8 store (16B/lane).
__global__ __launch_bounds__(256) void cvt4(const float* __restrict__ s0, short* __restrict__ d0, int n0,
                                            const float* __restrict__ s1, short* __restrict__ d1, int n1,
                                            const float* __restrict__ s2, short* __restrict__ d2, int n2,
                                            const float* __restrict__ s3, short* __restrict__ d3, int n3) {
  const float* s; short* d; int n;
  switch (blockIdx.y) {
    case 0:  s = s0; d = d0; n = n0; break;
    case 1:  s = s1; d = d1; n = n1; break;
    case 2:  s = s2; d = d2; n = n2; break;
    default: s = s3; d = d3; n = n3; break;
  }
  int stride = gridDim.x * blockDim.x * 8;
  for (int j = (blockIdx.x * blockDim.x + threadIdx.x) * 8; j < n; j += stride) {
    float4 a = *(const float4*)(s + j);
    float4 b = *(const float4*)(s + j + 4);
    s16x8 o;
    o[0] = f2bs(a.x); o[1] = f2bs(a.y); o[2] = f2bs(a.z); o[3] = f2bs(a.w);
    o[4] = f2bs(b.x); o[5] = f2bs(b.y); o[6] = f2bs(b.z); o[7] = f2bs(b.w);
    *(s16x8*)(d + j) = o;
  }
}

// pad K 588 -> 608 with zeros, row-major (vectorized: float4 -> s16x4)
__global__ __launch_bounds__(256) void cvt_pad(const float* __restrict__ s,
                                               short* __restrict__ d) {
  const int r = blockIdx.x, t = threadIdx.x;
  if (t < 147) {
    const float4 v = *(const float4*)(s + (size_t)r * 588 + t * 4);
    s16x4 o;
    o[0] = f2bs(v.x); o[1] = f2bs(v.y); o[2] = f2bs(v.z); o[3] = f2bs(v.w);
    *(s16x4*)(d + (size_t)r * 608 + t * 4) = o;
  } else if (t < 152) {
    s16x4 z = {};
    *(s16x4*)(d + (size_t)r * 608 + t * 4) = z;
  }
}

// ---------------------------------------------------------------- GEMM 128x128 (legacy pipelined)
// EPI: 0 = bf16 out, 1 = bf16 + exact GELU, 2 = f32 + residual, 3 = f32
template <int N, int K, int EPI, int CM, int CN>
__global__ __launch_bounds__(256) void gemm_bt(const short* __restrict__ A,
                                               const short* __restrict__ B,
                                               const float* __restrict__ bias,
                                               const float* __restrict__ resid,
                                               void* __restrict__ out) {
  static_assert(K % 32 == 0, "K");
  constexpr int NT = K / 32;
  static_assert(NT >= 3, "pipeline depth");
  constexpr int NX = N / 128, NY = 32;
  constexpr int nwg = NX * NY;
  static_assert(nwg % 8 == 0 && (nwg / 8) % (CM * CN) == 0, "chunk");
  static_assert(NX % CN == 0 && NY % CM == 0, "cells");
  __shared__ short lA[3][128 * 32];
  __shared__ short lB[3][128 * 32];

  const int o = blockIdx.x;
  const int wid = (o & 7) * (nwg / 8) + (o >> 3);
  constexpr int cellsz = CM * CN;
  const int cell = wid / cellsz, within = wid % cellsz;
  constexpr int cellsx = NX / CN;
  const int bm0 = ((cell / cellsx) * CM + within / CN) * 128;
  const int bn0 = ((cell % cellsx) * CN + within % CN) * 128;

  const int t = threadIdx.x, w = t >> 6, lane = t & 63;
  const int wr = w >> 1, wc = w & 1;
  f32x4 acc[4][4] = {};

  const int srow = t >> 2;
  const int scol = ((t & 3) ^ ((srow >> 1) & 3)) * 8;
  const short* aP = A + (size_t)(bm0 + srow) * K + scol;
  const short* bP = B + (size_t)(bn0 + srow) * K + scol;
  const int sdst0 = (w * 16) * 32;
  const int sdst1 = (64 + w * 16) * 32;

  const int lr = lane & 15;
  const int qx = ((lane >> 4) ^ ((lr >> 1) & 3)) * 8;

  auto stage = [&](int buf, int ko) {
    GLL16(aP + ko, &lA[buf][sdst0]);
    GLL16(aP + ko + (size_t)64 * K, &lA[buf][sdst1]);
    GLL16(bP + ko, &lB[buf][sdst0]);
    GLL16(bP + ko + (size_t)64 * K, &lB[buf][sdst1]);
  };

  stage(0, 0);
  stage(1, 32);
  stage(2, 64);

  int buf = 0;
  for (int kt = 0; kt < NT; ++kt) {
    if (kt < NT - 2)       asm volatile("s_waitcnt vmcnt(8)" ::: "memory");
    else if (kt == NT - 2) asm volatile("s_waitcnt vmcnt(4)" ::: "memory");
    else                   asm volatile("s_waitcnt vmcnt(0)" ::: "memory");
    __builtin_amdgcn_s_barrier();
    asm volatile("" ::: "memory");
    __builtin_amdgcn_sched_barrier(0);

    bf16x8 af[4], bg[4];
#pragma unroll
    for (int mi = 0; mi < 4; ++mi)
      af[mi] = *(const bf16x8*)&lA[buf][(wr * 64 + mi * 16 + lr) * 32 + qx];
#pragma unroll
    for (int ni = 0; ni < 4; ++ni)
      bg[ni] = *(const bf16x8*)&lB[buf][(wc * 64 + ni * 16 + lr) * 32 + qx];

    asm volatile("s_waitcnt lgkmcnt(0)" ::: "memory");
    __builtin_amdgcn_sched_barrier(0);
    __builtin_amdgcn_s_barrier();
    asm volatile("" ::: "memory");
    __builtin_amdgcn_sched_barrier(0);

    if (kt + 3 < NT) stage(buf, (kt + 3) * 32);
    __builtin_amdgcn_sched_barrier(0);

#pragma unroll
    for (int mi = 0; mi < 4; ++mi)
#pragma unroll
      for (int ni = 0; ni < 4; ++ni)
        acc[mi][ni] = __builtin_amdgcn_mfma_f32_16x16x32_bf16(af[mi], bg[ni],
                                                              acc[mi][ni], 0, 0, 0);
    buf = (buf == 2) ? 0 : buf + 1;
  }

  const int lg4 = (lane >> 4) * 4;
#pragma unroll
  for (int mi = 0; mi < 4; ++mi) {
#pragma unroll
    for (int ni = 0; ni < 4; ++ni) {
      const int row = bm0 + wr * 64 + mi * 16 + lg4;
      const int col = bn0 + wc * 64 + ni * 16 + lr;
      const float bc = bias[col];
#pragma unroll
      for (int r = 0; r < 4; ++r) {
        float v = acc[mi][ni][r] + bc;
        size_t idx = (size_t)(row + r) * N + col;
        if constexpr (EPI == 1) v = 0.5f * v * (1.0f + erff(v * 0.70710678118f));
        if constexpr (EPI == 0 || EPI == 1) ((short*)out)[idx] = f2bs(v);
        else if constexpr (EPI == 2) ((float*)out)[idx] = v + resid[idx];
        else ((float*)out)[idx] = v;
      }
    }
  }
}

// ---------------------------------------------------------------- GEMM 128x128, BK=64, 2 blocks/CU (split-K helper)
// EPI 5: bf16 partial at out + kc*4096*1024 (no bias).
template <int N, int KC, int LDK, int EPI, int CM, int CN, int KSPLIT>
__global__ __launch_bounds__(256, 2) void gemm128(const short* __restrict__ A,
                                                  const short* __restrict__ B,
                                                  const float* __restrict__ bias,
                                                  void* __restrict__ out) {
  static_assert(KC % 64 == 0, "K");
  constexpr int NKT = KC / 64;
  static_assert(NKT >= 4 && (NKT % 2) == 0, "ktiles");
  constexpr int NX = N / 128, NY = 32;
  constexpr int nwg = NX * NY * KSPLIT;
  constexpr int cellsz = CM * CN;
  static_assert(nwg % 8 == 0 && (nwg / 8) % cellsz == 0, "chunk");
  static_assert((NX * NY) % cellsz == 0, "cellspace");
  static_assert(NX % CN == 0 && NY % CM == 0, "cells");

  __shared__ short sA[2][128 * 64];
  __shared__ short sB[2][128 * 64];

  const int o = blockIdx.x;
  const int wid = (o & 7) * (nwg / 8) + (o >> 3);
  const int kc = wid / (NX * NY);
  const int rem = wid % (NX * NY);
  const int cell = rem / cellsz, within = rem % cellsz;
  constexpr int cellsx = NX / CN;
  const int bm0 = ((cell / cellsx) * CM + within / CN) * 128;
  const int bn0 = ((cell % cellsx) * CN + within % CN) * 128;

  const int t = threadIdx.x, w = t >> 6, lane = t & 63;
  const int wr = w >> 1, wc = w & 1;
  const int lr = lane & 15, lg = lane >> 4;

  const int srow = t >> 3;
  const int sch = (t & 7) ^ (srow & 7);
  const short* aS = A + (size_t)(bm0 + srow) * LDK + kc * KC + sch * 8;
  const short* bS = B + (size_t)(bn0 + srow) * LDK + kc * KC + sch * 8;
  const int ldst = w * 512;

  auto stage = [&](int d, int kt) {
    const size_t ko = (size_t)kt * 64;
#pragma unroll
    for (int q = 0; q < 4; ++q)
      GLL16(aS + (size_t)q * 32 * LDK + ko, &sA[d][q * 2048 + ldst]);
#pragma unroll
    for (int q = 0; q < 4; ++q)
      GLL16(bS + (size_t)q * 32 * LDK + ko, &sB[d][q * 2048 + ldst]);
  };

  f32x4 acc[4][4] = {};

  stage(0, 0);
  stage(1, 1);

#define TILE(tt, dd)                                                          \
  {                                                                           \
    if ((tt) + 1 < NKT) asm volatile("s_waitcnt vmcnt(8)" ::: "memory");      \
    else                asm volatile("s_waitcnt vmcnt(0)" ::: "memory");      \
    __builtin_amdgcn_s_barrier();                                             \
    bf16x8 af[2][4], bf[2][4];                                                \
    _Pragma("unroll")                                                         \
    for (int ks = 0; ks < 2; ++ks) {                                          \
      _Pragma("unroll")                                                       \
      for (int mi = 0; mi < 4; ++mi)                                          \
        af[ks][mi] = *(const bf16x8*)&sA[dd][(wr * 64 + mi * 16 + lr) * 64 +  \
                                             (((ks << 2) + lg) ^ (lr & 7)) * 8]; \
      _Pragma("unroll")                                                       \
      for (int ni = 0; ni < 4; ++ni)                                          \
        bf[ks][ni] = *(const bf16x8*)&sB[dd][(wc * 64 + ni * 16 + lr) * 64 +  \
                                             (((ks << 2) + lg) ^ (lr & 7)) * 8]; \
    }                                                                         \
    __builtin_amdgcn_s_setprio(1);                                            \
    _Pragma("unroll")                                                         \
    for (int ks = 0; ks < 2; ++ks)                                            \
      _Pragma("unroll")                                                       \
      for (int mi = 0; mi < 4; ++mi)                                          \
        _Pragma("unroll")                                                     \
        for (int ni = 0; ni < 4; ++ni)                                        \
          acc[mi][ni] = __builtin_amdgcn_mfma_f32_16x16x32_bf16(              \
              af[ks][mi], bf[ks][ni], acc[mi][ni], 0, 0, 0);                  \
    __builtin_amdgcn_s_setprio(0);                                            \
    __builtin_amdgcn_s_barrier();                                             \
    if ((tt) + 2 < NKT) stage(dd, (tt) + 2);                                  \
  }

  for (int kt = 0; kt < NKT; kt += 2) {
    TILE(kt, 0);
    TILE(kt + 1, 1);
  }
#undef TILE

  const int lg4 = lg * 4;
#pragma unroll
  for (int mi = 0; mi < 4; ++mi) {
#pragma unroll
    for (int ni = 0; ni < 4; ++ni) {
      const int row = bm0 + wr * 64 + mi * 16 + lg4;
      const int col = bn0 + wc * 64 + ni * 16 + lr;
      float bc = 0.f;
      if constexpr (EPI != 5) bc = bias[col];
#pragma unroll
      for (int r = 0; r < 4; ++r) {
        float v = acc[mi][ni][r] + bc;
        if constexpr (EPI == 1) {
          const float u = v * (0.7978845608f + 0.0356774081f * v * v);
          v = v / (1.0f + __expf(-2.0f * u));
        }
        if constexpr (EPI == 5)
          ((short*)out)[((size_t)kc << 22) + (size_t)(row + r) * N + col] = f2bs(v);
        else
          ((short*)out)[(size_t)(row + r) * N + col] = f2bs(v);
      }
    }
  }
}

// ---------------------------------------------------------------- GEMM 256x256, m201-style (R9 best)
template <int N, int KC, int LDK, int EPI, int CM, int CN, int KSPLIT>
__global__ __launch_bounds__(512, 2) void gemm256(const short* __restrict__ A,
                                                  const short* __restrict__ B,
                                                  const float* __restrict__ bias,
                                                  void* __restrict__ out) {
  static_assert(KC % 64 == 0, "K");
  constexpr int NKT = KC / 64;
  static_assert(NKT >= 2, "ktiles");
  constexpr int NXT = N / 256, MYT = 16;
  constexpr int nwg = NXT * MYT * KSPLIT;
  constexpr int cellsz = CM * CN;
  static_assert(nwg % 8 == 0 && (nwg / 8) % cellsz == 0, "chunk");
  static_assert((NXT * MYT) % cellsz == 0, "cellspace");
  static_assert(NXT % CN == 0 && MYT % CM == 0, "cells");

  __shared__ short sA[2][2][8192];
  __shared__ short sB[2][2][8192];

  const int o = blockIdx.x;
  const int wid = (o & 7) * (nwg / 8) + (o >> 3);
  const int kc = wid / (NXT * MYT);
  const int rem = wid % (NXT * MYT);
  const int cell = rem / cellsz, within = rem % cellsz;
  constexpr int cellsx = NXT / CN;
  const int bm0 = ((cell / cellsx) * CM + within / CN) * 256;
  const int bn0 = ((cell % cellsx) * CN + within % CN) * 256;

  const int tid = threadIdx.x, wv = tid >> 6, lane = tid & 63;
  const int wrow = wv >> 2, wcol = wv & 3;
  const int lr = lane & 15, lg = lane >> 4;

  const int sr0 = tid >> 2;
  const int sc0 = ((tid & 3) ^ ((sr0 >> 1) & 3)) * 8;
  const short* aS0 = A + (size_t)(bm0 + sr0) * LDK + kc * KC + sc0;
  const short* bS0 = B + (size_t)(bn0 + sr0) * LDK + kc * KC + sc0;
  const int ld0 = wv * 512, ld1 = 4096 + wv * 512;

  auto stageA = [&](int d, int h, int kt) {
    const int off = kt * 64 + h * 32;
    GLL16(aS0 + off, &sA[d][h][ld0]);
    GLL16(aS0 + off + (size_t)128 * LDK, &sA[d][h][ld1]);
  };
  auto stageB = [&](int d, int h, int kt) {
    const int off = kt * 64 + h * 32;
    GLL16(bS0 + off, &sB[d][h][ld0]);
    GLL16(bS0 + off + (size_t)128 * LDK, &sB[d][h][ld1]);
  };

  const int chR = (lg ^ ((lr >> 1) & 3)) * 8;
  const int rA0 = wrow * 128 + lr;
  const int rB0 = wcol * 64 + lr;

  f32x4 acc[8][4] = {};
  bf16x8 aF[4][2], bF[4][2];

  stageA(0, 0, 0); stageA(0, 1, 0);
  stageB(0, 0, 0); stageB(0, 1, 0);
  asm volatile("s_waitcnt vmcnt(0)" ::: "memory");
  __builtin_amdgcn_s_barrier();

#define RD_A(mh)                                                              \
  _Pragma("unroll")                                                           \
  for (int f = 0; f < 4; ++f) {                                               \
    aF[f][0] = *(const bf16x8*)&sA[r][0][(rA0 + (mh)*64 + f * 16) * 32 + chR];\
    aF[f][1] = *(const bf16x8*)&sA[r][1][(rA0 + (mh)*64 + f * 16) * 32 + chR];\
  }
#define RD_B2(n0)                                                             \
  _Pragma("unroll")                                                           \
  for (int n = 0; n < 2; ++n) {                                               \
    bF[(n0)+n][0] = *(const bf16x8*)&sB[r][0][(rB0 + ((n0)+n) * 16) * 32 + chR];\
    bF[(n0)+n][1] = *(const bf16x8*)&sB[r][1][(rB0 + ((n0)+n) * 16) * 32 + chR];\
  }
#define MM(ab, n0)                                                            \
  __builtin_amdgcn_s_setprio(1);                                              \
  _Pragma("unroll")                                                           \
  for (int ks = 0; ks < 2; ++ks)                                              \
    _Pragma("unroll")                                                         \
    for (int f = 0; f < 4; ++f)                                               \
      _Pragma("unroll")                                                       \
      for (int n = 0; n < 2; ++n)                                             \
        acc[(ab)+f][(n0)+n] = __builtin_amdgcn_mfma_f32_16x16x32_bf16(        \
            aF[f][ks], bF[(n0)+n][ks], acc[(ab)+f][(n0)+n], 0, 0, 0);         \
  __builtin_amdgcn_s_setprio(0);
#define BAR __builtin_amdgcn_s_barrier();
#define LGW asm volatile("s_waitcnt lgkmcnt(0)");

  for (int t = 0; t < NKT; ++t) {
    const int r = t & 1, sd = r ^ 1;
    const bool more = (t + 1 < NKT);
    RD_A(0); RD_B2(0);
    if (more) { stageA(sd, 0, t + 1); stageA(sd, 1, t + 1); }
    BAR; LGW; MM(0, 0); BAR;
    RD_B2(2);
    if (more) { stageB(sd, 0, t + 1); stageB(sd, 1, t + 1); }
    BAR; LGW; MM(0, 2); BAR;
    RD_A(1);
    BAR; LGW; MM(4, 2); BAR;
    MM(4, 0);
    asm volatile("s_waitcnt vmcnt(0)" ::: "memory");
    BAR;
  }
#undef RD_A
#undef RD_B2
#undef MM
#undef BAR
#undef LGW

  const int lg4 = lg * 4;
#pragma unroll
  for (int mh = 0; mh < 2; ++mh) {
#pragma unroll
    for (int f = 0; f < 4; ++f) {
#pragma unroll
      for (int n = 0; n < 4; ++n) {
        const int row = bm0 + wrow * 128 + mh * 64 + f * 16 + lg4;
        const int col = bn0 + wcol * 64 + n * 16 + lr;
        float bc = 0.f;
        if constexpr (EPI != 5) bc = bias[col];
#pragma unroll
        for (int r = 0; r < 4; ++r) {
          float v = acc[mh * 4 + f][n][r] + bc;
          if constexpr (EPI == 1) {
            const float u = v * (0.7978845608f + 0.0356774081f * v * v);
            v = v / (1.0f + __expf(-2.0f * u));
          }
          if constexpr (EPI == 5)
            ((short*)out)[((size_t)kc << 22) + (size_t)(row + r) * N + col] = f2bs(v);
          else
            ((short*)out)[(size_t)(row + r) * N + col] = f2bs(v);
        }
      }
    }
  }
}

// ---------------------------------------------------------------- split-K reduce (bf16 partials, last FC2)
__global__ __launch_bounds__(256) void fc2_reduce(const short* __restrict__ part,
                                                  const float* __restrict__ bias,
                                                  const float* __restrict__ resid,
                                                  float* __restrict__ dest) {
  const size_t i4 = ((size_t)blockIdx.x * 256 + threadIdx.x) * 4;
  const s16x4 a0 = *(const s16x4*)(part + i4);
  const s16x4 a1 = *(const s16x4*)(part + (1ull << 22) + i4);
  const s16x4 a2 = *(const s16x4*)(part + (2ull << 22) + i4);
  const s16x4 a3 = *(const s16x4*)(part + (3ull << 22) + i4);
  const float4 rv = *(const float4*)(resid + i4);
  const float4 bv = *(const float4*)(bias + (i4 & 1023));
  float4 o;
  o.x = bs2f(a0[0]) + bs2f(a1[0]) + bs2f(a2[0]) + bs2f(a3[0]) + rv.x + bv.x;
  o.y = bs2f(a0[1]) + bs2f(a1[1]) + bs2f(a2[1]) + bs2f(a3[1]) + rv.y + bv.y;
  o.z = bs2f(a0[2]) + bs2f(a1[2]) + bs2f(a2[2]) + bs2f(a3[2]) + rv.z + bv.z;
  o.w = bs2f(a0[3]) + bs2f(a1[3]) + bs2f(a2[3]) + bs2f(a3[3]) + rv.w + bv.w;
  *(float4*)(dest + i4) = o;
}

// ---------------------------------------------------------------- fused split-K reduce + LayerNorm (bf16 partials)
__global__ __launch_bounds__(256) void reduce_ln(const short* __restrict__ part,
                                                 const float* __restrict__ bias,
                                                 const float* __restrict__ resid,
                                                 const float* __restrict__ g,
                                                 const float* __restrict__ b,
                                                 float* __restrict__ X,
                                                 short* __restrict__ Y) {
  const int row = blockIdx.x, t = threadIdx.x, w = t >> 6, lane = t & 63;
  const size_t i4 = (size_t)row * 1024 + t * 4;
  const s16x4 a0 = *(const s16x4*)(part + i4);
  const s16x4 a1 = *(const s16x4*)(part + (1ull << 22) + i4);
  const s16x4 a2 = *(const s16x4*)(part + (2ull << 22) + i4);
  const s16x4 a3 = *(const s16x4*)(part + (3ull << 22) + i4);
  const float4 rv = *(const float4*)(resid + i4);
  const float4 bv = *(const float4*)(bias + t * 4);
  float4 v;
  v.x = bs2f(a0[0]) + bs2f(a1[0]) + bs2f(a2[0]) + bs2f(a3[0]) + rv.x + bv.x;
  v.y = bs2f(a0[1]) + bs2f(a1[1]) + bs2f(a2[1]) + bs2f(a3[1]) + rv.y + bv.y;
  v.z = bs2f(a0[2]) + bs2f(a1[2]) + bs2f(a2[2]) + bs2f(a3[2]) + rv.z + bv.z;
  v.w = bs2f(a0[3]) + bs2f(a1[3]) + bs2f(a2[3]) + bs2f(a3[3]) + rv.w + bv.w;
  *(float4*)(X + i4) = v;

  float s = v.x + v.y + v.z + v.w;
  float ss = v.x * v.x + v.y * v.y + v.z * v.z + v.w * v.w;
#pragma unroll
  for (int m = 1; m < 64; m <<= 1) { s += __shfl_xor(s, m); ss += __shfl_xor(ss, m); }
  __shared__ float rs[4], rss[4];
  if (lane == 0) { rs[w] = s; rss[w] = ss; }
  __syncthreads();
  s = rs[0] + rs[1] + rs[2] + rs[3];
  ss = rss[0] + rss[1] + rss[2] + rss[3];
  const float mean = s * (1.f / 1024.f);
  const float var = ss * (1.f / 1024.f) - mean * mean;
  const float rstd = rsqrtf(var + 1e-6f);
  const float4 gv = ((const float4*)g)[t];
  const float4 bb = ((const float4*)b)[t];
  s16x4 o;
  o[0] = f2bs((v.x - mean) * rstd * gv.x + bb.x);
  o[1] = f2bs((v.y - mean) * rstd * gv.y + bb.y);
  o[2] = f2bs((v.z - mean) * rstd * gv.z + bb.z);
  o[3] = f2bs((v.w - mean) * rstd * gv.w + bb.w);
  *(s16x4*)(Y + i4) = o;
}

// ---------------------------------------------------------------- LayerNorm -> bf16 (used once)
__global__ __launch_bounds__(256) void ln_fwd(const float* __restrict__ x,
                                              const float* __restrict__ g,
                                              const float* __restrict__ b,
                                              short* __restrict__ y) {
  const int row = blockIdx.x, t = threadIdx.x, w = t >> 6, lane = t & 63;
  const float4 v = ((const float4*)(x + (size_t)row * 1024))[t];
  float s = v.x + v.y + v.z + v.w;
  float ss = v.x * v.x + v.y * v.y + v.z * v.z + v.w * v.w;
#pragma unroll
  for (int m = 1; m < 64; m <<= 1) { s += __shfl_xor(s, m); ss += __shfl_xor(ss, m); }
  __shared__ float rs[4], rss[4];
  if (lane == 0) { rs[w] = s; rss[w] = ss; }
  __syncthreads();
  s = rs[0] + rs[1] + rs[2] + rs[3];
  ss = rss[0] + rss[1] + rss[2] + rss[3];
  const float mean = s * (1.f / 1024.f);
  const float var = ss * (1.f / 1024.f) - mean * mean;
  const float rstd = rsqrtf(var + 1e-6f);
  const float4 gv = ((const float4*)g)[t];
  const float4 bv = ((const float4*)b)[t];
  s16x4 o;
  o[0] = f2bs((v.x - mean) * rstd * gv.x + bv.x);
  o[1] = f2bs((v.y - mean) * rstd * gv.y + bv.y);
  o[2] = f2bs((v.z - mean) * rstd * gv.z + bv.z);
  o[3] = f2bs((v.w - mean) * rstd * gv.w + bv.w);
  *(s16x4*)(y + (size_t)row * 1024 + t * 4) = o;
}

// ---------------------------------------------------------------- pos-embed bilinear add
__global__ __launch_bounds__(256) void pos_add(float* __restrict__ x,
                                               const float* __restrict__ pe) {
  const int sidx = blockIdx.x;
  const int f = sidx & 1023;
  const int wq = 2 * ((f >> 2) & 15) + (f & 1);
  const int hq = 2 * (f >> 6) + ((f >> 1) & 1);
  const float gx = (wq + 0.5f) * 0.75f - 0.5f;
  const float gy = (hq + 0.5f) * 0.75f - 0.5f;
  const float fx = floorf(gx), fy = floorf(gy);
  const float wx = gx - fx, wy = gy - fy;
  int x0 = (int)fx, y0 = (int)fy;
  const int x0i = x0 < 0 ? 0 : (x0 > 23 ? 23 : x0);
  const int x1i = (x0 + 1) < 0 ? 0 : ((x0 + 1) > 23 ? 23 : x0 + 1);
  const int y0i = y0 < 0 ? 0 : (y0 > 23 ? 23 : y0);
  const int y1i = (y0 + 1) < 0 ? 0 : ((y0 + 1) > 23 ? 23 : y0 + 1);
  const float w00 = (1 - wy) * (1 - wx), w01 = (1 - wy) * wx;
  const float w10 = wy * (1 - wx), w11 = wy * wx;
  const int c = threadIdx.x * 4;
  const float4 p00 = *(const float4*)(pe + (size_t)(y0i * 24 + x0i) * 1024 + c);
  const float4 p01 = *(const float4*)(pe + (size_t)(y0i * 24 + x1i) * 1024 + c);
  const float4 p10 = *(const float4*)(pe + (size_t)(y1i * 24 + x0i) * 1024 + c);
  const float4 p11 = *(const float4*)(pe + (size_t)(y1i * 24 + x1i) * 1024 + c);
  float* xp = x + (size_t)sidx * 1024 + c;
  float4 xv = *(float4*)xp;
  xv.x += w00 * p00.x + w01 * p01.x + w10 * p10.x + w11 * p11.x;
  xv.y += w00 * p00.y + w01 * p01.y + w10 * p10.y + w11 * p11.y;
  xv.z += w00 * p00.z + w01 * p01.z + w10 * p10.z + w11 * p11.z;
  xv.w += w00 * p00.w + w01 * p01.w + w10 * p10.w + w11 * p11.w;
  *(float4*)xp = xv;
}

// ---------------------------------------------------------------- attention (flash, swapped, fixed-shift softmax)
// XCD-swizzled 1D grid (1024 blocks): wid = (o&7)*128 + (o>>3);
// bh = wid>>4, qb = wid&15 -> each XCD owns 8 complete (b,h) groups, so the
// 16 q-blocks sharing one K/V (256 KB) hit the same 4 MB L2 (T1 mechanism).
// psum accumulated per-lane across all kb; single cross-lane reduce at end.
__global__ __launch_bounds__(256) void attn_fwd(const short* __restrict__ qkv,
                                                short* __restrict__ outp) {
  __shared__ short lK[2][64 * 64];
  __shared__ short Vt[2][64 * 72];
  const int t = threadIdx.x, w = t >> 6, lane = t & 63;
  const int o = blockIdx.x;
  const int wid = (o & 7) * 128 + (o >> 3);
  const int bh = wid >> 4, qb = wid & 15;
  const int b = bh >> 4, h = bh & 15;
  const int sbase = b * 1024;
  const int q0 = qb * 64 + w * 16;
  const int lr = lane & 15, lg = lane >> 4;

  const short* qrow = qkv + (size_t)(sbase + q0 + lr) * 3072 + h * 64;
  const bf16x8 qf0 = *(const bf16x8*)(qrow + lg * 8);
  const bf16x8 qf1 = *(const bf16x8*)(qrow + 32 + lg * 8);

  const int krofs = t >> 3;
  const int kcol = ((t & 7) ^ (krofs & 7)) * 8;
  const short* ksrc = qkv + (size_t)(sbase + krofs) * 3072 + 1024 + h * 64 + kcol;
  const int vkv = t >> 2, vdp = t & 3;
  const short* vsrc = qkv + (size_t)(sbase + vkv) * 3072 + 2048 + h * 64 + vdp * 16;
  const int vph = vkv ^ (vdp << 4);

  f32x4 oacc[4] = {};
  float psacc = 0.f;

  s16x8 v0 = *(const s16x8*)vsrc;
  s16x8 v1 = *(const s16x8*)(vsrc + 8);
  GLL16(ksrc, &lK[0][(w * 8) * 64]);
  GLL16(ksrc + (size_t)32 * 3072, &lK[0][(32 + w * 8) * 64]);
#pragma unroll
  for (int j = 0; j < 8; ++j) Vt[0][(vdp * 16 + j) * 72 + vph] = v0[j];
#pragma unroll
  for (int j = 0; j < 8; ++j) Vt[0][(vdp * 16 + 8 + j) * 72 + vph] = v1[j];
  asm volatile("s_waitcnt vmcnt(0) lgkmcnt(0)" ::: "memory");
  __builtin_amdgcn_s_barrier();

  int buf = 0;
  for (int kb = 0; kb < 16; ++kb) {
    if (kb < 15) {
      const short* vs = vsrc + (size_t)(kb + 1) * 64 * 3072;
      v0 = *(const s16x8*)vs;
      v1 = *(const s16x8*)(vs + 8);
      const short* ks = ksrc + (size_t)(kb + 1) * 64 * 3072;
      GLL16(ks, &lK[buf ^ 1][(w * 8) * 64]);
      GLL16(ks + (size_t)32 * 3072, &lK[buf ^ 1][(32 + w * 8) * 64]);
    }

    f32x4 s[4];
    __builtin_amdgcn_s_setprio(1);
#pragma unroll
    for (int sub = 0; sub < 4; ++sub) {
      const int krow = (sub * 16 + lr) * 64;
      const bf16x8 kf0 = *(const bf16x8*)&lK[buf][krow + (lg ^ (lr & 7)) * 8];
      const bf16x8 kf1 = *(const bf16x8*)&lK[buf][krow + ((lg + 4) ^ (lr & 7)) * 8];
      f32x4 a = {};
      a = __builtin_amdgcn_mfma_f32_16x16x32_bf16(kf0, qf0, a, 0, 0, 0);
      a = __builtin_amdgcn_mfma_f32_16x16x32_bf16(kf1, qf1, a, 0, 0, 0);
      s[sub] = a;
    }
    __builtin_amdgcn_s_setprio(0);

    constexpr float SC = 0.125f * 1.44269504089f;
    s16x4 pb[4];
#pragma unroll
    for (int sub = 0; sub < 4; ++sub)
#pragma unroll
      for (int r = 0; r < 4; ++r) {
        const float p = exp2f(fmaf(s[sub][r], SC, -8.0f));
        psacc += p;
        pb[sub][r] = f2bs(p);
      }

    __builtin_amdgcn_s_setprio(1);
#pragma unroll
    for (int f = 0; f < 4; ++f) {
      const int vrow = (f * 16 + lr) * 72;
#pragma unroll
      for (int sub = 0; sub < 4; ++sub) {
        const s16x4 va = *(const s16x4*)&Vt[buf][vrow + ((sub ^ f) << 4) + lg * 4];
        oacc[f] = __builtin_amdgcn_mfma_f32_16x16x16bf16_1k(va, pb[sub], oacc[f], 0, 0, 0);
      }
    }
    __builtin_amdgcn_s_setprio(0);

    if (kb < 15) {
#pragma unroll
      for (int j = 0; j < 8; ++j) Vt[buf ^ 1][(vdp * 16 + j) * 72 + vph] = v0[j];
#pragma unroll
      for (int j = 0; j < 8; ++j) Vt[buf ^ 1][(vdp * 16 + 8 + j) * 72 + vph] = v1[j];
      asm volatile("s_waitcnt vmcnt(0) lgkmcnt(0)" ::: "memory");
      __builtin_amdgcn_s_barrier();
      buf ^= 1;
    }
  }

  psacc += __shfl_xor(psacc, 16);
  psacc += __shfl_xor(psacc, 32);
  const float inv = 1.0f / psacc;
  short* orow = outp + (size_t)(sbase + q0 + lr) * 1024 + h * 64;
#pragma unroll
  for (int f = 0; f < 4; ++f) {
    s16x4 ov;
    ov[0] = f2bs(oacc[f][0] * inv); ov[1] = f2bs(oacc[f][1] * inv);
    ov[2] = f2bs(oacc[f][2] * inv); ov[3] = f2bs(oacc[f][3] * inv);
    *(s16x4*)(orow + f * 16 + lg * 4) = ov;
  }
}

// ---------------------------------------------------------------- launch
extern "C" void kernel_launch(void* const* d_in, const int* in_sizes, int n_in,
                              void* d_out, int out_size, void* d_ws, size_t ws_size,
                              hipStream_t stream) {
  const float* pixel  = (const float*)d_in[0];
  const float* conv_w = (const float*)d_in[2];
  const float* conv_b = (const float*)d_in[3];
  const float* pos_e  = (const float*)d_in[4];
  const float* ln1_g  = (const float*)d_in[5];
  const float* ln1_b  = (const float*)d_in[6];
  const float* qkv_w  = (const float*)d_in[7];
  const float* qkv_b  = (const float*)d_in[8];
  const float* proj_w = (const float*)d_in[9];
  const float* proj_b = (const float*)d_in[10];
  const float* ln2_g  = (const float*)d_in[11];
  const float* ln2_b  = (const float*)d_in[12];
  const float* fc1_w  = (const float*)d_in[13];
  const float* fc1_b  = (const float*)d_in[14];
  const float* fc2_w  = (const float*)d_in[15];
  const float* fc2_b  = (const float*)d_in[16];

  char* ws = (char*)d_ws;
  short* wQKV  = (short*)(ws + 0);           // 25165824
  short* wPROJ = (short*)(ws + 25165824);    // 8388608
  short* wFC1  = (short*)(ws + 33554432);    // 33554432
  short* wFC2  = (short*)(ws + 67108864);    // 33554432
  float* X     = (float*)(ws + 100663296);   // 16777216
  short* Y     = (short*)(ws + 117440512);   // 8388608
  short* QKVB  = (short*)(ws + 125829120);   // 25165824
  short* ATTNO = (short*)(ws + 150994944);   // 8388608  (end 159383552)
  short* H     = QKVB;                       // alias
  short* WPIX  = QKVB;                       // alias, used only before layer 0
  short* WCONV = (short*)(ws + 125829120 + 4980736);
  short* PART  = (short*)(ws + 159383552);   // 33554432 (bf16 split-K partials)
  const bool wsbig = ws_size >= (size_t)159383552 + 33554432;

  cvt4<<<dim3(512, 4), 256, 0, stream>>>(
      qkv_w, wQKV, 4 * 3072 * 1024,
      proj_w, wPROJ, 4 * 1024 * 1024,
      fc1_w, wFC1, 4 * 4096 * 1024,
      fc2_w, wFC2, 4 * 1024 * 4096);
  cvt_pad<<<4096, 256, 0, stream>>>(pixel, WPIX);
  cvt_pad<<<1024, 256, 0, stream>>>(conv_w, WCONV);

  gemm_bt<1024, 608, 3, 4, 8><<<256, 256, 0, stream>>>(WPIX, WCONV, conv_b, nullptr, X);
  pos_add<<<4096, 256, 0, stream>>>(X, pos_e);
  ln_fwd<<<4096, 256, 0, stream>>>(X, ln1_g, ln1_b, Y);   // layer-0 ln1 only

  for (int i = 0; i < 4; ++i) {
    gemm256<3072, 1024, 1024, 0, 8, 3, 1><<<192, 512, 0, stream>>>(
        Y, wQKV + (size_t)i * 3072 * 1024, qkv_b + i * 3072, QKVB);
    attn_fwd<<<1024, 256, 0, stream>>>(QKVB, ATTNO);

    if (wsbig) {
      gemm128<1024, 256, 1024, 5, 8, 4, 4><<<1024, 256, 0, stream>>>(
          ATTNO, wPROJ + (size_t)i * 1024 * 1024, nullptr, PART);
      reduce_ln<<<4096, 256, 0, stream>>>(PART, proj_b + i * 1024, X,
                                          ln2_g + i * 1024, ln2_b + i * 1024, X, Y);
    } else {
      gemm_bt<1024, 1024, 2, 4, 8><<<256, 256, 0, stream>>>(
          ATTNO, wPROJ + (size_t)i * 1024 * 1024, proj_b + i * 1024, X, X);
      ln_fwd<<<4096, 256, 0, stream>>>(X, ln2_g + i * 1024, ln2_b + i * 1024, Y);
    }

    gemm256<4096, 1024, 1024, 1, 8, 4, 1><<<256, 512, 0, stream>>>(
        Y, wFC1 + (size_t)i * 4096 * 1024, fc1_b + i * 4096, H);

    if (wsbig) {
      gemm256<1024, 1024, 4096, 5, 8, 4, 4><<<256, 512, 0, stream>>>(
          H, wFC2 + (size_t)i * 1024 * 4096, nullptr, PART);
      if (i < 3) {
        reduce_ln<<<4096, 256, 0, stream>>>(PART, fc2_b + i * 1024, X,
                                            ln1_g + (i + 1) * 1024,
                                            ln1_b + (i + 1) * 1024, X, Y);
      } else {
        fc2_reduce<<<4096, 256, 0, stream>>>(PART, fc2_b + i * 1024, X,
                                             (float*)d_out);
      }
    } else {
      float* dest = (i < 3) ? X : (float*)d_out;
      gemm_bt<1024, 4096, 2, 4, 8><<<256, 256, 0, stream>>>(
          H, wFC2 + (size_t)i * 1024 * 4096, fc2_b + i * 1024, X, dest);
      if (i < 3)
        ln_fwd<<<4096, 256, 0, stream>>>(X, ln1_g + (i + 1) * 1024,
                                         ln1_b + (i + 1) * 1024, Y);
    }
  }
}

// Round 24
// 896.216 us; speedup vs baseline: 1.0037x; 1.0037x over previous
//
#include <hip/hip_runtime.h>
#include <math.h>

typedef __bf16 bf16x8 __attribute__((ext_vector_type(8)));
typedef float f32x4 __attribute__((ext_vector_type(4)));
typedef short s16x4 __attribute__((ext_vector_type(4)));
typedef short s16x8 __attribute__((ext_vector_type(8)));

static __device__ __forceinline__ short f2bs(float f) {
  return __builtin_bit_cast(short, (__bf16)f);
}
static __device__ __forceinline__ float bs2f(short s) {
  return __builtin_bit_cast(float, ((unsigned int)(unsigned short)s) << 16);
}

#define GLL16(gp, lp) __builtin_amdgcn_global_load_lds( \
    (const __attribute__((address_space(1))) void*)(gp), \
    (__attribute__((address_space(3))) void*)(lp), 16, 0, 0)

// ---------------------------------------------------------------- conversions
// 4 weight tensors f32->bf16 in ONE launch; blockIdx.y selects segment.
// 4 elem/thread (R22 best; 8-elem variant measured slower - fewer outstanding reqs).
__global__ __launch_bounds__(256) void cvt4(const float* __restrict__ s0, short* __restrict__ d0, int n0,
                                            const float* __restrict__ s1, short* __restrict__ d1, int n1,
                                            const float* __restrict__ s2, short* __restrict__ d2, int n2,
                                            const float* __restrict__ s3, short* __restrict__ d3, int n3) {
  const float* s; short* d; int n;
  switch (blockIdx.y) {
    case 0:  s = s0; d = d0; n = n0; break;
    case 1:  s = s1; d = d1; n = n1; break;
    case 2:  s = s2; d = d2; n = n2; break;
    default: s = s3; d = d3; n = n3; break;
  }
  int stride = gridDim.x * blockDim.x * 4;
  for (int j = (blockIdx.x * blockDim.x + threadIdx.x) * 4; j < n; j += stride) {
    float4 v = *(const float4*)(s + j);
    s16x4 o;
    o[0] = f2bs(v.x); o[1] = f2bs(v.y); o[2] = f2bs(v.z); o[3] = f2bs(v.w);
    *(s16x4*)(d + j) = o;
  }
}

// pad K 588 -> 608 with zeros, row-major (vectorized: float4 -> s16x4)
__global__ __launch_bounds__(256) void cvt_pad(const float* __restrict__ s,
                                               short* __restrict__ d) {
  const int r = blockIdx.x, t = threadIdx.x;
  if (t < 147) {
    const float4 v = *(const float4*)(s + (size_t)r * 588 + t * 4);
    s16x4 o;
    o[0] = f2bs(v.x); o[1] = f2bs(v.y); o[2] = f2bs(v.z); o[3] = f2bs(v.w);
    *(s16x4*)(d + (size_t)r * 608 + t * 4) = o;
  } else if (t < 152) {
    s16x4 z = {};
    *(s16x4*)(d + (size_t)r * 608 + t * 4) = z;
  }
}

// ---------------------------------------------------------------- GEMM 128x128 (legacy pipelined)
// EPI: 0 = bf16 out, 1 = bf16 + exact GELU, 2 = f32 + residual, 3 = f32
template <int N, int K, int EPI, int CM, int CN>
__global__ __launch_bounds__(256) void gemm_bt(const short* __restrict__ A,
                                               const short* __restrict__ B,
                                               const float* __restrict__ bias,
                                               const float* __restrict__ resid,
                                               void* __restrict__ out) {
  static_assert(K % 32 == 0, "K");
  constexpr int NT = K / 32;
  static_assert(NT >= 3, "pipeline depth");
  constexpr int NX = N / 128, NY = 32;
  constexpr int nwg = NX * NY;
  static_assert(nwg % 8 == 0 && (nwg / 8) % (CM * CN) == 0, "chunk");
  static_assert(NX % CN == 0 && NY % CM == 0, "cells");
  __shared__ short lA[3][128 * 32];
  __shared__ short lB[3][128 * 32];

  const int o = blockIdx.x;
  const int wid = (o & 7) * (nwg / 8) + (o >> 3);
  constexpr int cellsz = CM * CN;
  const int cell = wid / cellsz, within = wid % cellsz;
  constexpr int cellsx = NX / CN;
  const int bm0 = ((cell / cellsx) * CM + within / CN) * 128;
  const int bn0 = ((cell % cellsx) * CN + within % CN) * 128;

  const int t = threadIdx.x, w = t >> 6, lane = t & 63;
  const int wr = w >> 1, wc = w & 1;
  f32x4 acc[4][4] = {};

  const int srow = t >> 2;
  const int scol = ((t & 3) ^ ((srow >> 1) & 3)) * 8;
  const short* aP = A + (size_t)(bm0 + srow) * K + scol;
  const short* bP = B + (size_t)(bn0 + srow) * K + scol;
  const int sdst0 = (w * 16) * 32;
  const int sdst1 = (64 + w * 16) * 32;

  const int lr = lane & 15;
  const int qx = ((lane >> 4) ^ ((lr >> 1) & 3)) * 8;

  auto stage = [&](int buf, int ko) {
    GLL16(aP + ko, &lA[buf][sdst0]);
    GLL16(aP + ko + (size_t)64 * K, &lA[buf][sdst1]);
    GLL16(bP + ko, &lB[buf][sdst0]);
    GLL16(bP + ko + (size_t)64 * K, &lB[buf][sdst1]);
  };

  stage(0, 0);
  stage(1, 32);
  stage(2, 64);

  int buf = 0;
  for (int kt = 0; kt < NT; ++kt) {
    if (kt < NT - 2)       asm volatile("s_waitcnt vmcnt(8)" ::: "memory");
    else if (kt == NT - 2) asm volatile("s_waitcnt vmcnt(4)" ::: "memory");
    else                   asm volatile("s_waitcnt vmcnt(0)" ::: "memory");
    __builtin_amdgcn_s_barrier();
    asm volatile("" ::: "memory");
    __builtin_amdgcn_sched_barrier(0);

    bf16x8 af[4], bg[4];
#pragma unroll
    for (int mi = 0; mi < 4; ++mi)
      af[mi] = *(const bf16x8*)&lA[buf][(wr * 64 + mi * 16 + lr) * 32 + qx];
#pragma unroll
    for (int ni = 0; ni < 4; ++ni)
      bg[ni] = *(const bf16x8*)&lB[buf][(wc * 64 + ni * 16 + lr) * 32 + qx];

    asm volatile("s_waitcnt lgkmcnt(0)" ::: "memory");
    __builtin_amdgcn_sched_barrier(0);
    __builtin_amdgcn_s_barrier();
    asm volatile("" ::: "memory");
    __builtin_amdgcn_sched_barrier(0);

    if (kt + 3 < NT) stage(buf, (kt + 3) * 32);
    __builtin_amdgcn_sched_barrier(0);

#pragma unroll
    for (int mi = 0; mi < 4; ++mi)
#pragma unroll
      for (int ni = 0; ni < 4; ++ni)
        acc[mi][ni] = __builtin_amdgcn_mfma_f32_16x16x32_bf16(af[mi], bg[ni],
                                                              acc[mi][ni], 0, 0, 0);
    buf = (buf == 2) ? 0 : buf + 1;
  }

  const int lg4 = (lane >> 4) * 4;
#pragma unroll
  for (int mi = 0; mi < 4; ++mi) {
#pragma unroll
    for (int ni = 0; ni < 4; ++ni) {
      const int row = bm0 + wr * 64 + mi * 16 + lg4;
      const int col = bn0 + wc * 64 + ni * 16 + lr;
      const float bc = bias[col];
#pragma unroll
      for (int r = 0; r < 4; ++r) {
        float v = acc[mi][ni][r] + bc;
        size_t idx = (size_t)(row + r) * N + col;
        if constexpr (EPI == 1) v = 0.5f * v * (1.0f + erff(v * 0.70710678118f));
        if constexpr (EPI == 0 || EPI == 1) ((short*)out)[idx] = f2bs(v);
        else if constexpr (EPI == 2) ((float*)out)[idx] = v + resid[idx];
        else ((float*)out)[idx] = v;
      }
    }
  }
}

// ---------------------------------------------------------------- GEMM 128x128, BK=64, 2 blocks/CU (split-K helper)
// EPI 5: bf16 partial at out + kc*4096*1024 (no bias).
template <int N, int KC, int LDK, int EPI, int CM, int CN, int KSPLIT>
__global__ __launch_bounds__(256, 2) void gemm128(const short* __restrict__ A,
                                                  const short* __restrict__ B,
                                                  const float* __restrict__ bias,
                                                  void* __restrict__ out) {
  static_assert(KC % 64 == 0, "K");
  constexpr int NKT = KC / 64;
  static_assert(NKT >= 4 && (NKT % 2) == 0, "ktiles");
  constexpr int NX = N / 128, NY = 32;
  constexpr int nwg = NX * NY * KSPLIT;
  constexpr int cellsz = CM * CN;
  static_assert(nwg % 8 == 0 && (nwg / 8) % cellsz == 0, "chunk");
  static_assert((NX * NY) % cellsz == 0, "cellspace");
  static_assert(NX % CN == 0 && NY % CM == 0, "cells");

  __shared__ short sA[2][128 * 64];
  __shared__ short sB[2][128 * 64];

  const int o = blockIdx.x;
  const int wid = (o & 7) * (nwg / 8) + (o >> 3);
  const int kc = wid / (NX * NY);
  const int rem = wid % (NX * NY);
  const int cell = rem / cellsz, within = rem % cellsz;
  constexpr int cellsx = NX / CN;
  const int bm0 = ((cell / cellsx) * CM + within / CN) * 128;
  const int bn0 = ((cell % cellsx) * CN + within % CN) * 128;

  const int t = threadIdx.x, w = t >> 6, lane = t & 63;
  const int wr = w >> 1, wc = w & 1;
  const int lr = lane & 15, lg = lane >> 4;

  const int srow = t >> 3;
  const int sch = (t & 7) ^ (srow & 7);
  const short* aS = A + (size_t)(bm0 + srow) * LDK + kc * KC + sch * 8;
  const short* bS = B + (size_t)(bn0 + srow) * LDK + kc * KC + sch * 8;
  const int ldst = w * 512;

  auto stage = [&](int d, int kt) {
    const size_t ko = (size_t)kt * 64;
#pragma unroll
    for (int q = 0; q < 4; ++q)
      GLL16(aS + (size_t)q * 32 * LDK + ko, &sA[d][q * 2048 + ldst]);
#pragma unroll
    for (int q = 0; q < 4; ++q)
      GLL16(bS + (size_t)q * 32 * LDK + ko, &sB[d][q * 2048 + ldst]);
  };

  f32x4 acc[4][4] = {};

  stage(0, 0);
  stage(1, 1);

#define TILE(tt, dd)                                                          \
  {                                                                           \
    if ((tt) + 1 < NKT) asm volatile("s_waitcnt vmcnt(8)" ::: "memory");      \
    else                asm volatile("s_waitcnt vmcnt(0)" ::: "memory");      \
    __builtin_amdgcn_s_barrier();                                             \
    bf16x8 af[2][4], bf[2][4];                                                \
    _Pragma("unroll")                                                         \
    for (int ks = 0; ks < 2; ++ks) {                                          \
      _Pragma("unroll")                                                       \
      for (int mi = 0; mi < 4; ++mi)                                          \
        af[ks][mi] = *(const bf16x8*)&sA[dd][(wr * 64 + mi * 16 + lr) * 64 +  \
                                             (((ks << 2) + lg) ^ (lr & 7)) * 8]; \
      _Pragma("unroll")                                                       \
      for (int ni = 0; ni < 4; ++ni)                                          \
        bf[ks][ni] = *(const bf16x8*)&sB[dd][(wc * 64 + ni * 16 + lr) * 64 +  \
                                             (((ks << 2) + lg) ^ (lr & 7)) * 8]; \
    }                                                                         \
    __builtin_amdgcn_s_setprio(1);                                            \
    _Pragma("unroll")                                                         \
    for (int ks = 0; ks < 2; ++ks)                                            \
      _Pragma("unroll")                                                       \
      for (int mi = 0; mi < 4; ++mi)                                          \
        _Pragma("unroll")                                                     \
        for (int ni = 0; ni < 4; ++ni)                                        \
          acc[mi][ni] = __builtin_amdgcn_mfma_f32_16x16x32_bf16(              \
              af[ks][mi], bf[ks][ni], acc[mi][ni], 0, 0, 0);                  \
    __builtin_amdgcn_s_setprio(0);                                            \
    __builtin_amdgcn_s_barrier();                                             \
    if ((tt) + 2 < NKT) stage(dd, (tt) + 2);                                  \
  }

  for (int kt = 0; kt < NKT; kt += 2) {
    TILE(kt, 0);
    TILE(kt + 1, 1);
  }
#undef TILE

  const int lg4 = lg * 4;
#pragma unroll
  for (int mi = 0; mi < 4; ++mi) {
#pragma unroll
    for (int ni = 0; ni < 4; ++ni) {
      const int row = bm0 + wr * 64 + mi * 16 + lg4;
      const int col = bn0 + wc * 64 + ni * 16 + lr;
      float bc = 0.f;
      if constexpr (EPI != 5) bc = bias[col];
#pragma unroll
      for (int r = 0; r < 4; ++r) {
        float v = acc[mi][ni][r] + bc;
        if constexpr (EPI == 1) {
          const float u = v * (0.7978845608f + 0.0356774081f * v * v);
          v = v / (1.0f + __expf(-2.0f * u));
        }
        if constexpr (EPI == 5)
          ((short*)out)[((size_t)kc << 22) + (size_t)(row + r) * N + col] = f2bs(v);
        else
          ((short*)out)[(size_t)(row + r) * N + col] = f2bs(v);
      }
    }
  }
}

// ---------------------------------------------------------------- GEMM 256x256, m201-style (R9 best)
template <int N, int KC, int LDK, int EPI, int CM, int CN, int KSPLIT>
__global__ __launch_bounds__(512, 2) void gemm256(const short* __restrict__ A,
                                                  const short* __restrict__ B,
                                                  const float* __restrict__ bias,
                                                  void* __restrict__ out) {
  static_assert(KC % 64 == 0, "K");
  constexpr int NKT = KC / 64;
  static_assert(NKT >= 2, "ktiles");
  constexpr int NXT = N / 256, MYT = 16;
  constexpr int nwg = NXT * MYT * KSPLIT;
  constexpr int cellsz = CM * CN;
  static_assert(nwg % 8 == 0 && (nwg / 8) % cellsz == 0, "chunk");
  static_assert((NXT * MYT) % cellsz == 0, "cellspace");
  static_assert(NXT % CN == 0 && MYT % CM == 0, "cells");

  __shared__ short sA[2][2][8192];
  __shared__ short sB[2][2][8192];

  const int o = blockIdx.x;
  const int wid = (o & 7) * (nwg / 8) + (o >> 3);
  const int kc = wid / (NXT * MYT);
  const int rem = wid % (NXT * MYT);
  const int cell = rem / cellsz, within = rem % cellsz;
  constexpr int cellsx = NXT / CN;
  const int bm0 = ((cell / cellsx) * CM + within / CN) * 256;
  const int bn0 = ((cell % cellsx) * CN + within % CN) * 256;

  const int tid = threadIdx.x, wv = tid >> 6, lane = tid & 63;
  const int wrow = wv >> 2, wcol = wv & 3;
  const int lr = lane & 15, lg = lane >> 4;

  const int sr0 = tid >> 2;
  const int sc0 = ((tid & 3) ^ ((sr0 >> 1) & 3)) * 8;
  const short* aS0 = A + (size_t)(bm0 + sr0) * LDK + kc * KC + sc0;
  const short* bS0 = B + (size_t)(bn0 + sr0) * LDK + kc * KC + sc0;
  const int ld0 = wv * 512, ld1 = 4096 + wv * 512;

  auto stageA = [&](int d, int h, int kt) {
    const int off = kt * 64 + h * 32;
    GLL16(aS0 + off, &sA[d][h][ld0]);
    GLL16(aS0 + off + (size_t)128 * LDK, &sA[d][h][ld1]);
  };
  auto stageB = [&](int d, int h, int kt) {
    const int off = kt * 64 + h * 32;
    GLL16(bS0 + off, &sB[d][h][ld0]);
    GLL16(bS0 + off + (size_t)128 * LDK, &sB[d][h][ld1]);
  };

  const int chR = (lg ^ ((lr >> 1) & 3)) * 8;
  const int rA0 = wrow * 128 + lr;
  const int rB0 = wcol * 64 + lr;

  f32x4 acc[8][4] = {};
  bf16x8 aF[4][2], bF[4][2];

  stageA(0, 0, 0); stageA(0, 1, 0);
  stageB(0, 0, 0); stageB(0, 1, 0);
  asm volatile("s_waitcnt vmcnt(0)" ::: "memory");
  __builtin_amdgcn_s_barrier();

#define RD_A(mh)                                                              \
  _Pragma("unroll")                                                           \
  for (int f = 0; f < 4; ++f) {                                               \
    aF[f][0] = *(const bf16x8*)&sA[r][0][(rA0 + (mh)*64 + f * 16) * 32 + chR];\
    aF[f][1] = *(const bf16x8*)&sA[r][1][(rA0 + (mh)*64 + f * 16) * 32 + chR];\
  }
#define RD_B2(n0)                                                             \
  _Pragma("unroll")                                                           \
  for (int n = 0; n < 2; ++n) {                                               \
    bF[(n0)+n][0] = *(const bf16x8*)&sB[r][0][(rB0 + ((n0)+n) * 16) * 32 + chR];\
    bF[(n0)+n][1] = *(const bf16x8*)&sB[r][1][(rB0 + ((n0)+n) * 16) * 32 + chR];\
  }
#define MM(ab, n0)                                                            \
  __builtin_amdgcn_s_setprio(1);                                              \
  _Pragma("unroll")                                                           \
  for (int ks = 0; ks < 2; ++ks)                                              \
    _Pragma("unroll")                                                         \
    for (int f = 0; f < 4; ++f)                                               \
      _Pragma("unroll")                                                       \
      for (int n = 0; n < 2; ++n)                                             \
        acc[(ab)+f][(n0)+n] = __builtin_amdgcn_mfma_f32_16x16x32_bf16(        \
            aF[f][ks], bF[(n0)+n][ks], acc[(ab)+f][(n0)+n], 0, 0, 0);         \
  __builtin_amdgcn_s_setprio(0);
#define BAR __builtin_amdgcn_s_barrier();
#define LGW asm volatile("s_waitcnt lgkmcnt(0)");

  for (int t = 0; t < NKT; ++t) {
    const int r = t & 1, sd = r ^ 1;
    const bool more = (t + 1 < NKT);
    RD_A(0); RD_B2(0);
    if (more) { stageA(sd, 0, t + 1); stageA(sd, 1, t + 1); }
    BAR; LGW; MM(0, 0); BAR;
    RD_B2(2);
    if (more) { stageB(sd, 0, t + 1); stageB(sd, 1, t + 1); }
    BAR; LGW; MM(0, 2); BAR;
    RD_A(1);
    BAR; LGW; MM(4, 2); BAR;
    MM(4, 0);
    asm volatile("s_waitcnt vmcnt(0)" ::: "memory");
    BAR;
  }
#undef RD_A
#undef RD_B2
#undef MM
#undef BAR
#undef LGW

  const int lg4 = lg * 4;
#pragma unroll
  for (int mh = 0; mh < 2; ++mh) {
#pragma unroll
    for (int f = 0; f < 4; ++f) {
#pragma unroll
      for (int n = 0; n < 4; ++n) {
        const int row = bm0 + wrow * 128 + mh * 64 + f * 16 + lg4;
        const int col = bn0 + wcol * 64 + n * 16 + lr;
        float bc = 0.f;
        if constexpr (EPI != 5) bc = bias[col];
#pragma unroll
        for (int r = 0; r < 4; ++r) {
          float v = acc[mh * 4 + f][n][r] + bc;
          if constexpr (EPI == 1) {
            const float u = v * (0.7978845608f + 0.0356774081f * v * v);
            v = v / (1.0f + __expf(-2.0f * u));
          }
          if constexpr (EPI == 5)
            ((short*)out)[((size_t)kc << 22) + (size_t)(row + r) * N + col] = f2bs(v);
          else
            ((short*)out)[(size_t)(row + r) * N + col] = f2bs(v);
        }
      }
    }
  }
}

// ---------------------------------------------------------------- split-K reduce (bf16 partials, last FC2)
__global__ __launch_bounds__(256) void fc2_reduce(const short* __restrict__ part,
                                                  const float* __restrict__ bias,
                                                  const float* __restrict__ resid,
                                                  float* __restrict__ dest) {
  const size_t i4 = ((size_t)blockIdx.x * 256 + threadIdx.x) * 4;
  const s16x4 a0 = *(const s16x4*)(part + i4);
  const s16x4 a1 = *(const s16x4*)(part + (1ull << 22) + i4);
  const s16x4 a2 = *(const s16x4*)(part + (2ull << 22) + i4);
  const s16x4 a3 = *(const s16x4*)(part + (3ull << 22) + i4);
  const float4 rv = *(const float4*)(resid + i4);
  const float4 bv = *(const float4*)(bias + (i4 & 1023));
  float4 o;
  o.x = bs2f(a0[0]) + bs2f(a1[0]) + bs2f(a2[0]) + bs2f(a3[0]) + rv.x + bv.x;
  o.y = bs2f(a0[1]) + bs2f(a1[1]) + bs2f(a2[1]) + bs2f(a3[1]) + rv.y + bv.y;
  o.z = bs2f(a0[2]) + bs2f(a1[2]) + bs2f(a2[2]) + bs2f(a3[2]) + rv.z + bv.z;
  o.w = bs2f(a0[3]) + bs2f(a1[3]) + bs2f(a2[3]) + bs2f(a3[3]) + rv.w + bv.w;
  *(float4*)(dest + i4) = o;
}

// ---------------------------------------------------------------- fused split-K reduce + LayerNorm (bf16 partials)
__global__ __launch_bounds__(256) void reduce_ln(const short* __restrict__ part,
                                                 const float* __restrict__ bias,
                                                 const float* __restrict__ resid,
                                                 const float* __restrict__ g,
                                                 const float* __restrict__ b,
                                                 float* __restrict__ X,
                                                 short* __restrict__ Y) {
  const int row = blockIdx.x, t = threadIdx.x, w = t >> 6, lane = t & 63;
  const size_t i4 = (size_t)row * 1024 + t * 4;
  const s16x4 a0 = *(const s16x4*)(part + i4);
  const s16x4 a1 = *(const s16x4*)(part + (1ull << 22) + i4);
  const s16x4 a2 = *(const s16x4*)(part + (2ull << 22) + i4);
  const s16x4 a3 = *(const s16x4*)(part + (3ull << 22) + i4);
  const float4 rv = *(const float4*)(resid + i4);
  const float4 bv = *(const float4*)(bias + t * 4);
  float4 v;
  v.x = bs2f(a0[0]) + bs2f(a1[0]) + bs2f(a2[0]) + bs2f(a3[0]) + rv.x + bv.x;
  v.y = bs2f(a0[1]) + bs2f(a1[1]) + bs2f(a2[1]) + bs2f(a3[1]) + rv.y + bv.y;
  v.z = bs2f(a0[2]) + bs2f(a1[2]) + bs2f(a2[2]) + bs2f(a3[2]) + rv.z + bv.z;
  v.w = bs2f(a0[3]) + bs2f(a1[3]) + bs2f(a2[3]) + bs2f(a3[3]) + rv.w + bv.w;
  *(float4*)(X + i4) = v;

  float s = v.x + v.y + v.z + v.w;
  float ss = v.x * v.x + v.y * v.y + v.z * v.z + v.w * v.w;
#pragma unroll
  for (int m = 1; m < 64; m <<= 1) { s += __shfl_xor(s, m); ss += __shfl_xor(ss, m); }
  __shared__ float rs[4], rss[4];
  if (lane == 0) { rs[w] = s; rss[w] = ss; }
  __syncthreads();
  s = rs[0] + rs[1] + rs[2] + rs[3];
  ss = rss[0] + rss[1] + rss[2] + rss[3];
  const float mean = s * (1.f / 1024.f);
  const float var = ss * (1.f / 1024.f) - mean * mean;
  const float rstd = rsqrtf(var + 1e-6f);
  const float4 gv = ((const float4*)g)[t];
  const float4 bb = ((const float4*)b)[t];
  s16x4 o;
  o[0] = f2bs((v.x - mean) * rstd * gv.x + bb.x);
  o[1] = f2bs((v.y - mean) * rstd * gv.y + bb.y);
  o[2] = f2bs((v.z - mean) * rstd * gv.z + bb.z);
  o[3] = f2bs((v.w - mean) * rstd * gv.w + bb.w);
  *(s16x4*)(Y + i4) = o;
}

// ---------------------------------------------------------------- LayerNorm -> bf16 (used once)
__global__ __launch_bounds__(256) void ln_fwd(const float* __restrict__ x,
                                              const float* __restrict__ g,
                                              const float* __restrict__ b,
                                              short* __restrict__ y) {
  const int row = blockIdx.x, t = threadIdx.x, w = t >> 6, lane = t & 63;
  const float4 v = ((const float4*)(x + (size_t)row * 1024))[t];
  float s = v.x + v.y + v.z + v.w;
  float ss = v.x * v.x + v.y * v.y + v.z * v.z + v.w * v.w;
#pragma unroll
  for (int m = 1; m < 64; m <<= 1) { s += __shfl_xor(s, m); ss += __shfl_xor(ss, m); }
  __shared__ float rs[4], rss[4];
  if (lane == 0) { rs[w] = s; rss[w] = ss; }
  __syncthreads();
  s = rs[0] + rs[1] + rs[2] + rs[3];
  ss = rss[0] + rss[1] + rss[2] + rss[3];
  const float mean = s * (1.f / 1024.f);
  const float var = ss * (1.f / 1024.f) - mean * mean;
  const float rstd = rsqrtf(var + 1e-6f);
  const float4 gv = ((const float4*)g)[t];
  const float4 bv = ((const float4*)b)[t];
  s16x4 o;
  o[0] = f2bs((v.x - mean) * rstd * gv.x + bv.x);
  o[1] = f2bs((v.y - mean) * rstd * gv.y + bv.y);
  o[2] = f2bs((v.z - mean) * rstd * gv.z + bv.z);
  o[3] = f2bs((v.w - mean) * rstd * gv.w + bv.w);
  *(s16x4*)(y + (size_t)row * 1024 + t * 4) = o;
}

// ---------------------------------------------------------------- pos-embed bilinear add
__global__ __launch_bounds__(256) void pos_add(float* __restrict__ x,
                                               const float* __restrict__ pe) {
  const int sidx = blockIdx.x;
  const int f = sidx & 1023;
  const int wq = 2 * ((f >> 2) & 15) + (f & 1);
  const int hq = 2 * (f >> 6) + ((f >> 1) & 1);
  const float gx = (wq + 0.5f) * 0.75f - 0.5f;
  const float gy = (hq + 0.5f) * 0.75f - 0.5f;
  const float fx = floorf(gx), fy = floorf(gy);
  const float wx = gx - fx, wy = gy - fy;
  int x0 = (int)fx, y0 = (int)fy;
  const int x0i = x0 < 0 ? 0 : (x0 > 23 ? 23 : x0);
  const int x1i = (x0 + 1) < 0 ? 0 : ((x0 + 1) > 23 ? 23 : x0 + 1);
  const int y0i = y0 < 0 ? 0 : (y0 > 23 ? 23 : y0);
  const int y1i = (y0 + 1) < 0 ? 0 : ((y0 + 1) > 23 ? 23 : y0 + 1);
  const float w00 = (1 - wy) * (1 - wx), w01 = (1 - wy) * wx;
  const float w10 = wy * (1 - wx), w11 = wy * wx;
  const int c = threadIdx.x * 4;
  const float4 p00 = *(const float4*)(pe + (size_t)(y0i * 24 + x0i) * 1024 + c);
  const float4 p01 = *(const float4*)(pe + (size_t)(y0i * 24 + x1i) * 1024 + c);
  const float4 p10 = *(const float4*)(pe + (size_t)(y1i * 24 + x0i) * 1024 + c);
  const float4 p11 = *(const float4*)(pe + (size_t)(y1i * 24 + x1i) * 1024 + c);
  float* xp = x + (size_t)sidx * 1024 + c;
  float4 xv = *(float4*)xp;
  xv.x += w00 * p00.x + w01 * p01.x + w10 * p10.x + w11 * p11.x;
  xv.y += w00 * p00.y + w01 * p01.y + w10 * p10.y + w11 * p11.y;
  xv.z += w00 * p00.z + w01 * p01.z + w10 * p10.z + w11 * p11.z;
  xv.w += w00 * p00.w + w01 * p01.w + w10 * p10.w + w11 * p11.w;
  *(float4*)xp = xv;
}

// ---------------------------------------------------------------- attention (flash, swapped, fixed-shift softmax)
// XCD-swizzled 1D grid (1024 blocks): wid = (o&7)*128 + (o>>3);
// bh = wid>>4, qb = wid&15 -> each XCD owns 8 complete (b,h) groups, so the
// 16 q-blocks sharing one K/V (256 KB) hit the same 4 MB L2 (T1 mechanism).
// psum accumulated per-lane across all kb; single cross-lane reduce at end.
__global__ __launch_bounds__(256) void attn_fwd(const short* __restrict__ qkv,
                                                short* __restrict__ outp) {
  __shared__ short lK[2][64 * 64];
  __shared__ short Vt[2][64 * 72];
  const int t = threadIdx.x, w = t >> 6, lane = t & 63;
  const int o = blockIdx.x;
  const int wid = (o & 7) * 128 + (o >> 3);
  const int bh = wid >> 4, qb = wid & 15;
  const int b = bh >> 4, h = bh & 15;
  const int sbase = b * 1024;
  const int q0 = qb * 64 + w * 16;
  const int lr = lane & 15, lg = lane >> 4;

  const short* qrow = qkv + (size_t)(sbase + q0 + lr) * 3072 + h * 64;
  const bf16x8 qf0 = *(const bf16x8*)(qrow + lg * 8);
  const bf16x8 qf1 = *(const bf16x8*)(qrow + 32 + lg * 8);

  const int krofs = t >> 3;
  const int kcol = ((t & 7) ^ (krofs & 7)) * 8;
  const short* ksrc = qkv + (size_t)(sbase + krofs) * 3072 + 1024 + h * 64 + kcol;
  const int vkv = t >> 2, vdp = t & 3;
  const short* vsrc = qkv + (size_t)(sbase + vkv) * 3072 + 2048 + h * 64 + vdp * 16;
  const int vph = vkv ^ (vdp << 4);

  f32x4 oacc[4] = {};
  float psacc = 0.f;

  s16x8 v0 = *(const s16x8*)vsrc;
  s16x8 v1 = *(const s16x8*)(vsrc + 8);
  GLL16(ksrc, &lK[0][(w * 8) * 64]);
  GLL16(ksrc + (size_t)32 * 3072, &lK[0][(32 + w * 8) * 64]);
#pragma unroll
  for (int j = 0; j < 8; ++j) Vt[0][(vdp * 16 + j) * 72 + vph] = v0[j];
#pragma unroll
  for (int j = 0; j < 8; ++j) Vt[0][(vdp * 16 + 8 + j) * 72 + vph] = v1[j];
  asm volatile("s_waitcnt vmcnt(0) lgkmcnt(0)" ::: "memory");
  __builtin_amdgcn_s_barrier();

  int buf = 0;
  for (int kb = 0; kb < 16; ++kb) {
    if (kb < 15) {
      const short* vs = vsrc + (size_t)(kb + 1) * 64 * 3072;
      v0 = *(const s16x8*)vs;
      v1 = *(const s16x8*)(vs + 8);
      const short* ks = ksrc + (size_t)(kb + 1) * 64 * 3072;
      GLL16(ks, &lK[buf ^ 1][(w * 8) * 64]);
      GLL16(ks + (size_t)32 * 3072, &lK[buf ^ 1][(32 + w * 8) * 64]);
    }

    f32x4 s[4];
    __builtin_amdgcn_s_setprio(1);
#pragma unroll
    for (int sub = 0; sub < 4; ++sub) {
      const int krow = (sub * 16 + lr) * 64;
      const bf16x8 kf0 = *(const bf16x8*)&lK[buf][krow + (lg ^ (lr & 7)) * 8];
      const bf16x8 kf1 = *(const bf16x8*)&lK[buf][krow + ((lg + 4) ^ (lr & 7)) * 8];
      f32x4 a = {};
      a = __builtin_amdgcn_mfma_f32_16x16x32_bf16(kf0, qf0, a, 0, 0, 0);
      a = __builtin_amdgcn_mfma_f32_16x16x32_bf16(kf1, qf1, a, 0, 0, 0);
      s[sub] = a;
    }
    __builtin_amdgcn_s_setprio(0);

    constexpr float SC = 0.125f * 1.44269504089f;
    s16x4 pb[4];
#pragma unroll
    for (int sub = 0; sub < 4; ++sub)
#pragma unroll
      for (int r = 0; r < 4; ++r) {
        const float p = exp2f(fmaf(s[sub][r], SC, -8.0f));
        psacc += p;
        pb[sub][r] = f2bs(p);
      }

    __builtin_amdgcn_s_setprio(1);
#pragma unroll
    for (int f = 0; f < 4; ++f) {
      const int vrow = (f * 16 + lr) * 72;
#pragma unroll
      for (int sub = 0; sub < 4; ++sub) {
        const s16x4 va = *(const s16x4*)&Vt[buf][vrow + ((sub ^ f) << 4) + lg * 4];
        oacc[f] = __builtin_amdgcn_mfma_f32_16x16x16bf16_1k(va, pb[sub], oacc[f], 0, 0, 0);
      }
    }
    __builtin_amdgcn_s_setprio(0);

    if (kb < 15) {
#pragma unroll
      for (int j = 0; j < 8; ++j) Vt[buf ^ 1][(vdp * 16 + j) * 72 + vph] = v0[j];
#pragma unroll
      for (int j = 0; j < 8; ++j) Vt[buf ^ 1][(vdp * 16 + 8 + j) * 72 + vph] = v1[j];
      asm volatile("s_waitcnt vmcnt(0) lgkmcnt(0)" ::: "memory");
      __builtin_amdgcn_s_barrier();
      buf ^= 1;
    }
  }

  psacc += __shfl_xor(psacc, 16);
  psacc += __shfl_xor(psacc, 32);
  const float inv = 1.0f / psacc;
  short* orow = outp + (size_t)(sbase + q0 + lr) * 1024 + h * 64;
#pragma unroll
  for (int f = 0; f < 4; ++f) {
    s16x4 ov;
    ov[0] = f2bs(oacc[f][0] * inv); ov[1] = f2bs(oacc[f][1] * inv);
    ov[2] = f2bs(oacc[f][2] * inv); ov[3] = f2bs(oacc[f][3] * inv);
    *(s16x4*)(orow + f * 16 + lg * 4) = ov;
  }
}

// ---------------------------------------------------------------- launch
extern "C" void kernel_launch(void* const* d_in, const int* in_sizes, int n_in,
                              void* d_out, int out_size, void* d_ws, size_t ws_size,
                              hipStream_t stream) {
  const float* pixel  = (const float*)d_in[0];
  const float* conv_w = (const float*)d_in[2];
  const float* conv_b = (const float*)d_in[3];
  const float* pos_e  = (const float*)d_in[4];
  const float* ln1_g  = (const float*)d_in[5];
  const float* ln1_b  = (const float*)d_in[6];
  const float* qkv_w  = (const float*)d_in[7];
  const float* qkv_b  = (const float*)d_in[8];
  const float* proj_w = (const float*)d_in[9];
  const float* proj_b = (const float*)d_in[10];
  const float* ln2_g  = (const float*)d_in[11];
  const float* ln2_b  = (const float*)d_in[12];
  const float* fc1_w  = (const float*)d_in[13];
  const float* fc1_b  = (const float*)d_in[14];
  const float* fc2_w  = (const float*)d_in[15];
  const float* fc2_b  = (const float*)d_in[16];

  char* ws = (char*)d_ws;
  short* wQKV  = (short*)(ws + 0);           // 25165824
  short* wPROJ = (short*)(ws + 25165824);    // 8388608
  short* wFC1  = (short*)(ws + 33554432);    // 33554432
  short* wFC2  = (short*)(ws + 67108864);    // 33554432
  float* X     = (float*)(ws + 100663296);   // 16777216
  short* Y     = (short*)(ws + 117440512);   // 8388608
  short* QKVB  = (short*)(ws + 125829120);   // 25165824
  short* ATTNO = (short*)(ws + 150994944);   // 8388608  (end 159383552)
  short* H     = QKVB;                       // alias
  short* WPIX  = QKVB;                       // alias, used only before layer 0
  short* WCONV = (short*)(ws + 125829120 + 4980736);
  short* PART  = (short*)(ws + 159383552);   // 33554432 (bf16 split-K partials)
  const bool wsbig = ws_size >= (size_t)159383552 + 33554432;

  cvt4<<<dim3(512, 4), 256, 0, stream>>>(
      qkv_w, wQKV, 4 * 3072 * 1024,
      proj_w, wPROJ, 4 * 1024 * 1024,
      fc1_w, wFC1, 4 * 4096 * 1024,
      fc2_w, wFC2, 4 * 1024 * 4096);
  cvt_pad<<<4096, 256, 0, stream>>>(pixel, WPIX);
  cvt_pad<<<1024, 256, 0, stream>>>(conv_w, WCONV);

  gemm_bt<1024, 608, 3, 4, 8><<<256, 256, 0, stream>>>(WPIX, WCONV, conv_b, nullptr, X);
  pos_add<<<4096, 256, 0, stream>>>(X, pos_e);
  ln_fwd<<<4096, 256, 0, stream>>>(X, ln1_g, ln1_b, Y);   // layer-0 ln1 only

  for (int i = 0; i < 4; ++i) {
    gemm256<3072, 1024, 1024, 0, 8, 3, 1><<<192, 512, 0, stream>>>(
        Y, wQKV + (size_t)i * 3072 * 1024, qkv_b + i * 3072, QKVB);
    attn_fwd<<<1024, 256, 0, stream>>>(QKVB, ATTNO);

    if (wsbig) {
      gemm128<1024, 256, 1024, 5, 8, 4, 4><<<1024, 256, 0, stream>>>(
          ATTNO, wPROJ + (size_t)i * 1024 * 1024, nullptr, PART);
      reduce_ln<<<4096, 256, 0, stream>>>(PART, proj_b + i * 1024, X,
                                          ln2_g + i * 1024, ln2_b + i * 1024, X, Y);
    } else {
      gemm_bt<1024, 1024, 2, 4, 8><<<256, 256, 0, stream>>>(
          ATTNO, wPROJ + (size_t)i * 1024 * 1024, proj_b + i * 1024, X, X);
      ln_fwd<<<4096, 256, 0, stream>>>(X, ln2_g + i * 1024, ln2_b + i * 1024, Y);
    }

    gemm256<4096, 1024, 1024, 1, 8, 4, 1><<<256, 512, 0, stream>>>(
        Y, wFC1 + (size_t)i * 4096 * 1024, fc1_b + i * 4096, H);

    if (wsbig) {
      gemm256<1024, 1024, 4096, 5, 8, 4, 4><<<256, 512, 0, stream>>>(
          H, wFC2 + (size_t)i * 1024 * 4096, nullptr, PART);
      if (i < 3) {
        reduce_ln<<<4096, 256, 0, stream>>>(PART, fc2_b + i * 1024, X,
                                            ln1_g + (i + 1) * 1024,
                                            ln1_b + (i + 1) * 1024, X, Y);
      } else {
        fc2_reduce<<<4096, 256, 0, stream>>>(PART, fc2_b + i * 1024, X,
                                             (float*)d_out);
      }
    } else {
      float* dest = (i < 3) ? X : (float*)d_out;
      gemm_bt<1024, 4096, 2, 4, 8><<<256, 256, 0, stream>>>(
          H, wFC2 + (size_t)i * 1024 * 4096, fc2_b + i * 1024, X, dest);
      if (i < 3)
        ln_fwd<<<4096, 256, 0, stream>>>(X, ln1_g + (i + 1) * 1024,
                                         ln1_b + (i + 1) * 1024, Y);
    }
  }
}